// Round 9
// baseline (188.741 us; speedup 1.0000x reference)
//
#include <hip/hip_runtime.h>
#include <math.h>

#define NMEL   40
#define NCEP   13
#define BATCH  1024
#define NSAMP  16000
#define NFRAME 49
#define PI_F   3.14159265358979323846f

// d_ws float layout
#define WS_WIN  0        // 640 floats: Hann window
#define WS_R    640      // 512 float2: W_1024^k, k=0..511 (1024 floats)
#define WS_DT   1664     // 520 floats: DCT * 1/sqrt(80) * lifter, [40][13]
#define WS_BT   2184     // f16 area: Bt[48][544] mel weights transposed (13056 floats)
#define WS_TOT  15240

typedef _Float16 half8 __attribute__((ext_vector_type(8)));
typedef __fp16   fp16x2 __attribute__((ext_vector_type(2)));
typedef float f32x4 __attribute__((ext_vector_type(4)));

// Compiler-only ordering fence (DS ops of one wave execute in order).
#define WAVE_FENCE() { __builtin_amdgcn_wave_barrier(); asm volatile("" ::: "memory"); }

// radix-2 DIF butterfly on register arrays
#define BFLY(i0, i1, wr, wi) {                        \
    float tr = zr[i0] - zr[i1], ti = zi[i0] - zi[i1]; \
    zr[i0] += zr[i1]; zi[i0] += zi[i1];               \
    zr[i1] = tr*(wr) - ti*(wi);                       \
    zi[i1] = tr*(wi) + ti*(wr); }

__device__ __forceinline__ unsigned pk_f16(float a, float b) {
    fp16x2 h = __builtin_amdgcn_cvt_pkrtz(a, b);
    union { fp16x2 h; unsigned u; } cvt; cvt.h = h;
    return cvt.u;
}

// ---------------------------------------------------------------------------
// Prep: window / twiddle / DCT tables + transposed, padded f16 mel weights.
// ---------------------------------------------------------------------------
__global__ __launch_bounds__(256) void mfcc_prep(
    const float* __restrict__ mel_fb, float* __restrict__ ws)
{
    const int idx = blockIdx.x * 256 + threadIdx.x;   // grid = 64 blocks

    _Float16* bt = (_Float16*)(ws + WS_BT);
    for (int i = idx; i < 48 * 544; i += 64 * 256) {
        int n = i / 544, k = i - n * 544;
        float v = (n < NMEL && k < 513) ? mel_fb[k * NMEL + n] : 0.0f;
        bt[i] = (_Float16)v;
    }

    if (idx < 640 + 512 + 520) {
        int i = idx;
        if (i < 640) {
            ws[WS_WIN + i] = 0.5f - 0.5f * cosf(2.0f * PI_F * (float)i / 640.0f);
        } else if (i < 1152) {
            int k = i - 640;
            float s, c;
            sincosf(-2.0f * PI_F * (float)k / 1024.0f, &s, &c);
            ((float2*)(ws + WS_R))[k] = make_float2(c, s);
        } else {
            int j = i - 1152;
            int m = j / 13, c0 = j - m * 13;
            float d    = 2.0f * cosf(PI_F * (2.0f * m + 1.0f) * (float)c0 / 80.0f);
            float lift = 1.0f + 11.0f * sinf(PI_F * (float)c0 / 22.0f);
            ws[WS_DT + j] = d * 0.11180339887498949f * lift;   // 1/sqrt(80)
        }
    }
}

// ---------------------------------------------------------------------------
// Stage 1: 16 frames per block (4 waves x 4 sequential FFTs).
// r9: (a) real-split twiddles read from an LDS copy of the table instead of
// 16 hoisted VGPRs (r8: VGPR=104 capped 4 waves/SIMD); (b) next frame's
// input is prefetched into registers before the current FFT body, so HBM
// latency overlaps a whole FFT instead of stalling each frame start.
// ---------------------------------------------------------------------------
__global__ __launch_bounds__(256) void mfcc_stage1(
    const float* __restrict__ wave, const float* __restrict__ ws,
    float* __restrict__ out)
{
    // LDS: float2 Z[4][576] overlaid by f16 mag[16][552]; f16 lm[16][40];
    // float2 Rlds[512] twiddle copy.
    __shared__ __align__(16) char smem[4 * 576 * 8 + 16 * 40 * 2];
    __shared__ __align__(16) float2 Rlds[512];
    char* smemc = smem;
    _Float16* lm = (_Float16*)(smem + 4 * 576 * 8);  // [16][40] f16

    const int tid = threadIdx.x;
    const int wv  = tid >> 6;
    const int L   = tid & 63;
    const int s   = L & 7;

    float2* Z = (float2*)smem + wv * 576;            // wave-private FFT buffer
    const float2* R   = (const float2*)(ws + WS_R);
    const float2* win = (const float2*)(ws + WS_WIN);

    // copy twiddle table to LDS (2 float2 per thread, coalesced)
    #pragma unroll
    for (int i = tid; i < 512; i += 256) Rlds[i] = R[i];

    // ---- hoist stage twiddles + window into registers (once per wave) ----
    float2 twA[4], twB[2], twC, twD[4], twE[2], twF, winv[5];
    #pragma unroll
    for (int j = 0; j < 4; ++j) twA[j] = R[2 * (L + 64 * j)];
    #pragma unroll
    for (int j = 0; j < 2; ++j) twB[j] = R[4 * (L + 64 * j)];
    twC = R[8 * L];
    #pragma unroll
    for (int j = 0; j < 4; ++j) twD[j] = R[128 * j + 16 * s];
    #pragma unroll
    for (int j = 0; j < 2; ++j) twE[j] = R[256 * j + 32 * s];
    twF = R[64 * s];
    #pragma unroll
    for (int j = 0; j < 5; ++j) winv[j] = win[L + 64 * j];

    __syncthreads();     // Rlds visible to all waves

    uint4 mgp[4];          // per-frame packed f16 magnitudes (8 per lane)
    float m512v[4] = {0.0f, 0.0f, 0.0f, 0.0f};

    // input prefetch: double-buffered 5x float2 per frame
    float2 xb0[5], xb1[5];
    {
        const int frame = blockIdx.x * 16 + wv * 4;
        const int b = frame / NFRAME;
        const int f = frame - b * NFRAME;
        const float2* p = (const float2*)(wave + (size_t)b * NSAMP + (size_t)f * 320);
        #pragma unroll
        for (int j = 0; j < 5; ++j) xb0[j] = p[L + 64 * j];
    }

    #pragma unroll
    for (int fi = 0; fi < 4; ++fi) {
        float2* cur = (fi & 1) ? xb1 : xb0;
        float2* nxt = (fi & 1) ? xb0 : xb1;
        if (fi < 3) {   // issue next frame's loads now; waited on next iter
            const int frame = blockIdx.x * 16 + wv * 4 + fi + 1;
            const int b = frame / NFRAME;
            const int f = frame - b * NFRAME;
            const float2* p = (const float2*)(wave + (size_t)b * NSAMP + (size_t)f * 320);
            #pragma unroll
            for (int j = 0; j < 5; ++j) nxt[j] = p[L + 64 * j];
        }

        float zr[8], zi[8];
        #pragma unroll
        for (int j = 0; j < 8; ++j) { zr[j] = 0.0f; zi[j] = 0.0f; }
        // z[n] = x[2n]*w[2n] + i*x[2n+1]*w[2n+1], n = L + 64j (nonzero j<5)
        #pragma unroll
        for (int j = 0; j < 5; ++j) {
            zr[j] = cur[j].x * winv[j].x;
            zi[j] = cur[j].y * winv[j].y;
        }

        // ---- register stages on coset n = L + 64j ----
        #pragma unroll
        for (int j = 0; j < 4; ++j) BFLY(j, j + 4, twA[j].x, twA[j].y);   // 512
        #pragma unroll
        for (int g = 0; g < 8; g += 4) {                                  // 256
            #pragma unroll
            for (int j = 0; j < 2; ++j) BFLY(g + j, g + j + 2, twB[j].x, twB[j].y);
        }
        #pragma unroll
        for (int i0 = 0; i0 < 8; i0 += 2) BFLY(i0, i0 + 1, twC.x, twC.y); // 128

        // ---- exchange 1: n = L+64j -> n = 64*(L>>3) + 8j + s ----
        WAVE_FENCE();
        #pragma unroll
        for (int j = 0; j < 8; ++j) {
            int n = L + 64 * j;
            Z[n + (n >> 3)] = make_float2(zr[j], zi[j]);
        }
        WAVE_FENCE();
        #pragma unroll
        for (int j = 0; j < 8; ++j) {
            int n = (L >> 3) * 64 + 8 * j + s;
            float2 v = Z[n + (n >> 3)];
            zr[j] = v.x; zi[j] = v.y;
        }

        // ---- register stages on coset q = 8j + s within 64-blocks ----
        #pragma unroll
        for (int j = 0; j < 4; ++j) BFLY(j, j + 4, twD[j].x, twD[j].y);   // 64
        #pragma unroll
        for (int g = 0; g < 8; g += 4) {                                  // 32
            #pragma unroll
            for (int j = 0; j < 2; ++j) BFLY(g + j, g + j + 2, twE[j].x, twE[j].y);
        }
        #pragma unroll
        for (int i0 = 0; i0 < 8; i0 += 2) BFLY(i0, i0 + 1, twF.x, twF.y); // 16

        // ---- exchange 2: -> contiguous n = 8L + j ----
        WAVE_FENCE();
        #pragma unroll
        for (int j = 0; j < 8; ++j) {
            int n = (L >> 3) * 64 + 8 * j + s;
            Z[n + (n >> 6)] = make_float2(zr[j], zi[j]);
        }
        WAVE_FENCE();
        {
            int base = 8 * L + (L >> 3);
            #pragma unroll
            for (int j = 0; j < 8; ++j) {
                float2 v = Z[base + j];
                zr[j] = v.x; zi[j] = v.y;
            }
        }

        // ---- register stages on q = j (size 8,4,2) ----
        {
            const float C = 0.70710678118654752f;
            const float w8r[4] = { 1.0f,  C, 0.0f, -C };
            const float w8i[4] = { 0.0f, -C, -1.0f, -C };
            #pragma unroll
            for (int j = 0; j < 4; ++j) BFLY(j, j + 4, w8r[j], w8i[j]);
            #pragma unroll
            for (int g = 0; g < 8; g += 4) {
                BFLY(g + 0, g + 2, 1.0f, 0.0f);
                BFLY(g + 1, g + 3, 0.0f, -1.0f);
            }
            #pragma unroll
            for (int i0 = 0; i0 < 8; i0 += 2) BFLY(i0, i0 + 1, 1.0f, 0.0f);
        }

        // ---- write Z[k] at true k = rev3(j)*64 + rev6(L), pad (k>>6) ----
        WAVE_FENCE();
        {
            const int rev3t[8] = { 0, 4, 2, 6, 1, 5, 3, 7 };
            int r6 = (int)(__brev((unsigned)L) >> 26);
            #pragma unroll
            for (int j = 0; j < 8; ++j) {
                int k = rev3t[j] * 64 + r6;
                Z[k + rev3t[j]] = make_float2(zr[j], zi[j]);
            }
        }
        WAVE_FENCE();

        // ---- real-split + |X| for k = 8L + j; split twiddle from Rlds ----
        float mg[8];
        #pragma unroll
        for (int j = 0; j < 8; ++j) {
            int k = 8 * L + j;
            float2 wS = Rlds[k & 511];       // k<512 except unused lane63/j7 path
            if (k == 0) {                    // lane 0, j 0 only
                float2 z0 = Z[0];
                mg[j]     = fabsf(z0.x + z0.y);
                m512v[fi] = fabsf(z0.x - z0.y);
            } else {
                int n2 = 512 - k;
                float2 A  = Z[k  + (k  >> 6)];
                float2 Bv = Z[n2 + (n2 >> 6)];
                float xer = 0.5f * (A.x + Bv.x), xei = 0.5f * (A.y - Bv.y);
                float xo  = 0.5f * (A.y + Bv.y), xoi = -0.5f * (A.x - Bv.x);
                float xr = xer + wS.x * xo - wS.y * xoi;
                float xi = xei + wS.x * xoi + wS.y * xo;
                mg[j] = sqrtf(xr * xr + xi * xi);
            }
        }
        mgp[fi].x = pk_f16(mg[0], mg[1]);
        mgp[fi].y = pk_f16(mg[2], mg[3]);
        mgp[fi].z = pk_f16(mg[4], mg[5]);
        mgp[fi].w = pk_f16(mg[6], mg[7]);
        WAVE_FENCE();  // Z reads ordered before next frame's writes
    }

    // ---- all FFTs done: overlay mag tile [16][552] f16 onto smem ----
    __syncthreads();
    #pragma unroll
    for (int fi = 0; fi < 4; ++fi) {
        const int row = wv * 4 + fi;
        *(uint4*)(smemc + row * 1104 + 16 * L) = mgp[fi];
        if (L < 20) {   // zero pad bins [512..552), bin 512 = m512
            unsigned v = (L == 0) ? pk_f16(m512v[fi], 0.0f) : 0u;
            *(unsigned*)(smemc + row * 1104 + 1024 + 4 * L) = v;
        }
    }
    __syncthreads();

    // ---- mel projection: D[16 frames][16 mels] per wave, K = 544 ----
    if (wv < 3) {
        const int nl = L & 15, q = L >> 4;
        const char* ap = smemc + nl * 1104 + q * 16;                // A: frame rows
        const _Float16* btp = (const _Float16*)(ws + WS_BT)
                              + (size_t)(wv * 16 + nl) * 544 + q * 8;
        f32x4 acc = {0.0f, 0.0f, 0.0f, 0.0f};
        #pragma unroll
        for (int kk = 0; kk < 17; ++kk) {
            half8 a = *(const half8*)(ap + kk * 64);
            half8 b = *(const half8*)(btp + kk * 32);
            acc = __builtin_amdgcn_mfma_f32_16x16x32_f16(a, b, acc, 0, 0, 0);
        }
        const int mel = wv * 16 + nl;
        if (mel < NMEL) {
            #pragma unroll
            for (int r = 0; r < 4; ++r) {
                int fl = q * 4 + r;                 // C/D: row=(lane>>4)*4+r
                lm[fl * NMEL + mel] = (_Float16)__logf(acc[r] + 1e-6f);
            }
        }
    }
    __syncthreads();

    // ---- DCT + scale + lifter, fp32: 208 threads = 16 frames x 13 ceps ----
    if (tid < 16 * NCEP) {
        const int fl = tid / NCEP, c = tid - fl * NCEP;
        float acc = 0.0f;
        #pragma unroll
        for (int m = 0; m < NMEL; ++m)
            acc += (float)lm[fl * NMEL + m] * ws[WS_DT + m * 13 + c];
        out[(size_t)(blockIdx.x * 16 + fl) * (3 * NCEP) + c] = acc;
    }
}

// ---------------------------------------------------------------------------
// Stage 2: per-batch deltas.
// ---------------------------------------------------------------------------
__global__ __launch_bounds__(128) void mfcc_stage2(float* __restrict__ out)
{
    __shared__ float x [NFRAME * NCEP];
    __shared__ float d1[NFRAME * NCEP];

    const int b = blockIdx.x;
    const int tid = threadIdx.x;
    const int TC = NFRAME * NCEP;

    for (int i = tid; i < TC; i += 128) {
        const int t = i / NCEP, c = i - t * NCEP;
        x[i] = out[((size_t)b * NFRAME + t) * (3 * NCEP) + c];
    }
    __syncthreads();

    for (int i = tid; i < TC; i += 128) {
        const int t = i / NCEP, c = i - t * NCEP;
        float acc = 0.0f;
        #pragma unroll
        for (int k = -2; k <= 2; ++k) {
            if (k == 0) continue;
            int tt = t + k;
            tt = tt < 0 ? 0 : (tt > NFRAME - 1 ? NFRAME - 1 : tt);
            acc += (float)k * x[tt * NCEP + c];
        }
        d1[i] = acc * 0.1f;
    }
    __syncthreads();

    for (int i = tid; i < TC; i += 128) {
        const int t = i / NCEP, c = i - t * NCEP;
        float acc = 0.0f;
        #pragma unroll
        for (int k = -2; k <= 2; ++k) {
            if (k == 0) continue;
            int tt = t + k;
            tt = tt < 0 ? 0 : (tt > NFRAME - 1 ? NFRAME - 1 : tt);
            acc += (float)k * d1[tt * NCEP + c];
        }
        const size_t base = ((size_t)b * NFRAME + t) * (3 * NCEP);
        out[base +     NCEP + c] = d1[i];
        out[base + 2 * NCEP + c] = acc * 0.1f;
    }
}

extern "C" void kernel_launch(void* const* d_in, const int* in_sizes, int n_in,
                              void* d_out, int out_size, void* d_ws, size_t ws_size,
                              hipStream_t stream)
{
    const float* wave   = (const float*)d_in[0];   // [1024][16000] f32
    const float* mel_fb = (const float*)d_in[1];   // [513][40] f32
    float* out = (float*)d_out;                    // [1024][49][39][1] f32
    float* ws  = (float*)d_ws;

    mfcc_prep<<<64, 256, 0, stream>>>(mel_fb, ws);
    mfcc_stage1<<<(BATCH * NFRAME) / 16, 256, 0, stream>>>(wave, ws, out);
    mfcc_stage2<<<BATCH, 128, 0, stream>>>(out);
}

// Round 10
// 176.379 us; speedup vs baseline: 1.0701x; 1.0701x over previous
//
#include <hip/hip_runtime.h>
#include <math.h>

#define NMEL   40
#define NCEP   13
#define BATCH  1024
#define NSAMP  16000
#define NFRAME 49
#define PI_F   3.14159265358979323846f

// d_ws float layout
#define WS_WIN  0        // 640 floats: Hann window
#define WS_R    640      // 512 float2: W_1024^k, k=0..511 (1024 floats)
#define WS_DT   1664     // 520 floats: DCT * 1/sqrt(80) * lifter, [40][13]
#define WS_BT   2184     // f16 area: Bt[48][544] mel weights transposed (13056 floats)
#define WS_TOT  15240

typedef _Float16 half8 __attribute__((ext_vector_type(8)));
typedef __fp16   fp16x2 __attribute__((ext_vector_type(2)));
typedef float f32x4 __attribute__((ext_vector_type(4)));

// Compiler-only ordering fence (DS ops of one wave execute in order).
#define WAVE_FENCE() { __builtin_amdgcn_wave_barrier(); asm volatile("" ::: "memory"); }

// radix-2 DIF butterfly on register arrays
#define BFLY(i0, i1, wr, wi) {                        \
    float tr = zr[i0] - zr[i1], ti = zi[i0] - zi[i1]; \
    zr[i0] += zr[i1]; zi[i0] += zi[i1];               \
    zr[i1] = tr*(wr) - ti*(wi);                       \
    zi[i1] = tr*(wi) + ti*(wr); }

__device__ __forceinline__ unsigned pk_f16(float a, float b) {
    fp16x2 h = __builtin_amdgcn_cvt_pkrtz(a, b);
    union { fp16x2 h; unsigned u; } cvt; cvt.h = h;
    return cvt.u;
}

// ---------------------------------------------------------------------------
// Prep: window / twiddle / DCT tables + transposed, padded f16 mel weights.
// ---------------------------------------------------------------------------
__global__ __launch_bounds__(256) void mfcc_prep(
    const float* __restrict__ mel_fb, float* __restrict__ ws)
{
    const int idx = blockIdx.x * 256 + threadIdx.x;   // grid = 64 blocks

    _Float16* bt = (_Float16*)(ws + WS_BT);
    for (int i = idx; i < 48 * 544; i += 64 * 256) {
        int n = i / 544, k = i - n * 544;
        float v = (n < NMEL && k < 513) ? mel_fb[k * NMEL + n] : 0.0f;
        bt[i] = (_Float16)v;
    }

    if (idx < 640 + 512 + 520) {
        int i = idx;
        if (i < 640) {
            ws[WS_WIN + i] = 0.5f - 0.5f * cosf(2.0f * PI_F * (float)i / 640.0f);
        } else if (i < 1152) {
            int k = i - 640;
            float s, c;
            sincosf(-2.0f * PI_F * (float)k / 1024.0f, &s, &c);
            ((float2*)(ws + WS_R))[k] = make_float2(c, s);
        } else {
            int j = i - 1152;
            int m = j / 13, c0 = j - m * 13;
            float d    = 2.0f * cosf(PI_F * (2.0f * m + 1.0f) * (float)c0 / 80.0f);
            float lift = 1.0f + 11.0f * sinf(PI_F * (float)c0 / 22.0f);
            ws[WS_DT + j] = d * 0.11180339887498949f * lift;   // 1/sqrt(80)
        }
    }
}

// ---------------------------------------------------------------------------
// Stage 1: 16 frames per block (4 waves x 4 sequential FFTs).
// r10: the kernel is LDS-issue-bound (r8 DS demand ~= wall; conflicts = 26%
// of DS time). All LDS phases use slot(x) = x + 2*(x>>3) padding (Z stride
// 640): writes land <=2-way-conflict-free, all reads are lane-contiguous
// 16B-aligned -> ds_read_b128. Exchange 1 is "swapped": write scattered,
// read contiguous (was the reverse).
// ---------------------------------------------------------------------------
__global__ __launch_bounds__(256) void mfcc_stage1(
    const float* __restrict__ wave, const float* __restrict__ ws,
    float* __restrict__ out)
{
    // LDS: float2 Z[4][640] overlaid by f16 mag[16][552]; + f16 lm[16][40]
    __shared__ __align__(16) char smem[4 * 640 * 8 + 16 * 40 * 2];
    char* smemc = smem;
    _Float16* lm = (_Float16*)(smem + 4 * 640 * 8);  // [16][40] f16

    const int tid = threadIdx.x;
    const int wv  = tid >> 6;
    const int L   = tid & 63;
    const int s   = L & 7;
    const int a   = L >> 3;

    float2* Z = (float2*)smem + wv * 640;            // wave-private FFT buffer
    const float2* R   = (const float2*)(ws + WS_R);
    const float2* win = (const float2*)(ws + WS_WIN);

    // ---- hoist all loop-invariant tables into registers (once per wave) ----
    float2 twA[4], twB[2], twC, twD[4], twE[2], twF, twS[8], winv[5];
    #pragma unroll
    for (int j = 0; j < 4; ++j) twA[j] = R[2 * (L + 64 * j)];
    #pragma unroll
    for (int j = 0; j < 2; ++j) twB[j] = R[4 * (L + 64 * j)];
    twC = R[8 * L];
    #pragma unroll
    for (int j = 0; j < 4; ++j) twD[j] = R[128 * j + 16 * s];
    #pragma unroll
    for (int j = 0; j < 2; ++j) twE[j] = R[256 * j + 32 * s];
    twF = R[64 * s];
    #pragma unroll
    for (int j = 0; j < 8; ++j) twS[j] = R[8 * L + j];   // real-split W_1024^k
    #pragma unroll
    for (int j = 0; j < 5; ++j) winv[j] = win[L + 64 * j];

    uint4 mgp[4];          // per-frame packed f16 magnitudes (8 per lane)
    float m512v[4] = {0.0f, 0.0f, 0.0f, 0.0f};

    #pragma unroll
    for (int fi = 0; fi < 4; ++fi) {
        const int frame = blockIdx.x * 16 + wv * 4 + fi;
        const int b = frame / NFRAME;
        const int f = frame - b * NFRAME;
        const float2* xin = (const float2*)(wave + (size_t)b * NSAMP + (size_t)f * 320);

        float zr[8], zi[8];
        #pragma unroll
        for (int j = 0; j < 8; ++j) { zr[j] = 0.0f; zi[j] = 0.0f; }
        // z[n] = x[2n]*w[2n] + i*x[2n+1]*w[2n+1], n = L + 64j (nonzero j<5)
        #pragma unroll
        for (int j = 0; j < 5; ++j) {
            float2 x = xin[L + 64 * j];
            zr[j] = x.x * winv[j].x;
            zi[j] = x.y * winv[j].y;
        }

        // ---- register stages on coset n = L + 64j ----
        #pragma unroll
        for (int j = 0; j < 4; ++j) BFLY(j, j + 4, twA[j].x, twA[j].y);   // 512
        #pragma unroll
        for (int g = 0; g < 8; g += 4) {                                  // 256
            #pragma unroll
            for (int j = 0; j < 2; ++j) BFLY(g + j, g + j + 2, twB[j].x, twB[j].y);
        }
        #pragma unroll
        for (int i0 = 0; i0 < 8; i0 += 2) BFLY(i0, i0 + 1, twC.x, twC.y); // 128

        // ---- exchange 1 (swapped): element n=L+64j -> slot 80j+10s+a;
        //      read lane-contiguous slots 10L+j as 2x b128 ----
        WAVE_FENCE();
        #pragma unroll
        for (int j = 0; j < 8; ++j)
            Z[80 * j + 10 * s + a] = make_float2(zr[j], zi[j]);
        WAVE_FENCE();
        {
            float4 q0 = *(float4*)&Z[10 * L + 0];
            float4 q1 = *(float4*)&Z[10 * L + 2];
            float4 q2 = *(float4*)&Z[10 * L + 4];
            float4 q3 = *(float4*)&Z[10 * L + 6];
            zr[0] = q0.x; zi[0] = q0.y; zr[1] = q0.z; zi[1] = q0.w;
            zr[2] = q1.x; zi[2] = q1.y; zr[3] = q1.z; zi[3] = q1.w;
            zr[4] = q2.x; zi[4] = q2.y; zr[5] = q2.z; zi[5] = q2.w;
            zr[6] = q3.x; zi[6] = q3.y; zr[7] = q3.z; zi[7] = q3.w;
        }
        // now lane L holds n = 64*(L>>3) + 8j + s (same as before)

        // ---- register stages on coset q = 8j + s within 64-blocks ----
        #pragma unroll
        for (int j = 0; j < 4; ++j) BFLY(j, j + 4, twD[j].x, twD[j].y);   // 64
        #pragma unroll
        for (int g = 0; g < 8; g += 4) {                                  // 32
            #pragma unroll
            for (int j = 0; j < 2; ++j) BFLY(g + j, g + j + 2, twE[j].x, twE[j].y);
        }
        #pragma unroll
        for (int i0 = 0; i0 < 8; i0 += 2) BFLY(i0, i0 + 1, twF.x, twF.y); // 16

        // ---- exchange 2: element n=64a+8j+s -> slot(n) = 80a+10j+s;
        //      read slots 10L+j (= slot(8L+j)) as 2x b128 ----
        WAVE_FENCE();
        #pragma unroll
        for (int j = 0; j < 8; ++j)
            Z[80 * a + 10 * j + s] = make_float2(zr[j], zi[j]);
        WAVE_FENCE();
        {
            float4 q0 = *(float4*)&Z[10 * L + 0];
            float4 q1 = *(float4*)&Z[10 * L + 2];
            float4 q2 = *(float4*)&Z[10 * L + 4];
            float4 q3 = *(float4*)&Z[10 * L + 6];
            zr[0] = q0.x; zi[0] = q0.y; zr[1] = q0.z; zi[1] = q0.w;
            zr[2] = q1.x; zi[2] = q1.y; zr[3] = q1.z; zi[3] = q1.w;
            zr[4] = q2.x; zi[4] = q2.y; zr[5] = q2.z; zi[5] = q2.w;
            zr[6] = q3.x; zi[6] = q3.y; zr[7] = q3.z; zi[7] = q3.w;
        }

        // ---- register stages on q = j (size 8,4,2) ----
        {
            const float C = 0.70710678118654752f;
            const float w8r[4] = { 1.0f,  C, 0.0f, -C };
            const float w8i[4] = { 0.0f, -C, -1.0f, -C };
            #pragma unroll
            for (int j = 0; j < 4; ++j) BFLY(j, j + 4, w8r[j], w8i[j]);
            #pragma unroll
            for (int g = 0; g < 8; g += 4) {
                BFLY(g + 0, g + 2, 1.0f, 0.0f);
                BFLY(g + 1, g + 3, 0.0f, -1.0f);
            }
            #pragma unroll
            for (int i0 = 0; i0 < 8; i0 += 2) BFLY(i0, i0 + 1, 1.0f, 0.0f);
        }

        // ---- write X[k] at slot(k), k = rev3(j)*64 + rev6(L) ----
        WAVE_FENCE();
        {
            const int rev3t[8] = { 0, 4, 2, 6, 1, 5, 3, 7 };
            int r6 = (int)(__brev((unsigned)L) >> 26);
            int u  = r6 + 2 * (r6 >> 3);
            #pragma unroll
            for (int j = 0; j < 8; ++j)
                Z[80 * rev3t[j] + u] = make_float2(zr[j], zi[j]);
        }
        WAVE_FENCE();

        // ---- real-split + |X|, k = 8L+j. A-side slot(k)=10L+j (2x b128);
        //      B-side slot(512-k)=638-10L-j for j>=1 (2x b128 window), j=0 at
        //      640-10L (b64). ----
        float Ax[8], Ay[8], Bx[8], By[8];
        {
            float4 a0 = *(float4*)&Z[10 * L + 0];
            float4 a1 = *(float4*)&Z[10 * L + 2];
            float4 a2 = *(float4*)&Z[10 * L + 4];
            float4 a3 = *(float4*)&Z[10 * L + 6];
            Ax[0] = a0.x; Ay[0] = a0.y; Ax[1] = a0.z; Ay[1] = a0.w;
            Ax[2] = a1.x; Ay[2] = a1.y; Ax[3] = a1.z; Ay[3] = a1.w;
            Ax[4] = a2.x; Ay[4] = a2.y; Ax[5] = a2.z; Ay[5] = a2.w;
            Ax[6] = a3.x; Ay[6] = a3.y; Ax[7] = a3.z; Ay[7] = a3.w;
            float4 t0 = *(float4*)&Z[630 - 10 * L + 0];   // i=0,1 (j=8,7)
            float4 t1 = *(float4*)&Z[630 - 10 * L + 2];   // i=2,3 (j=6,5)
            float4 t2 = *(float4*)&Z[630 - 10 * L + 4];   // i=4,5 (j=4,3)
            float4 t3 = *(float4*)&Z[630 - 10 * L + 6];   // i=6,7 (j=2,1)
            float2 b0 = Z[640 - 10 * L];                  // j=0 (garbage if L==0)
            Bx[0] = b0.x;  By[0] = b0.y;
            Bx[7] = t0.z;  By[7] = t0.w;
            Bx[6] = t1.x;  By[6] = t1.y;
            Bx[5] = t1.z;  By[5] = t1.w;
            Bx[4] = t2.x;  By[4] = t2.y;
            Bx[3] = t2.z;  By[3] = t2.w;
            Bx[2] = t3.x;  By[2] = t3.y;
            Bx[1] = t3.z;  By[1] = t3.w;
        }
        float mg[8];
        #pragma unroll
        for (int j = 0; j < 8; ++j) {
            int k = 8 * L + j;
            if (k == 0) {                    // lane 0, j 0 only
                mg[j]     = fabsf(Ax[0] + Ay[0]);
                m512v[fi] = fabsf(Ax[0] - Ay[0]);
            } else {
                float xer = 0.5f * (Ax[j] + Bx[j]), xei = 0.5f * (Ay[j] - By[j]);
                float xo  = 0.5f * (Ay[j] + By[j]), xoi = -0.5f * (Ax[j] - Bx[j]);
                float xr = xer + twS[j].x * xo - twS[j].y * xoi;
                float xi = xei + twS[j].x * xoi + twS[j].y * xo;
                mg[j] = sqrtf(xr * xr + xi * xi);
            }
        }
        mgp[fi].x = pk_f16(mg[0], mg[1]);
        mgp[fi].y = pk_f16(mg[2], mg[3]);
        mgp[fi].z = pk_f16(mg[4], mg[5]);
        mgp[fi].w = pk_f16(mg[6], mg[7]);
        WAVE_FENCE();  // Z reads ordered before next frame's writes
    }

    // ---- all FFTs done: overlay mag tile [16][552] f16 onto smem ----
    __syncthreads();
    #pragma unroll
    for (int fi = 0; fi < 4; ++fi) {
        const int row = wv * 4 + fi;
        *(uint4*)(smemc + row * 1104 + 16 * L) = mgp[fi];
        if (L < 20) {   // zero pad bins [512..552), bin 512 = m512
            unsigned v = (L == 0) ? pk_f16(m512v[fi], 0.0f) : 0u;
            *(unsigned*)(smemc + row * 1104 + 1024 + 4 * L) = v;
        }
    }
    __syncthreads();

    // ---- mel projection: D[16 frames][16 mels] per wave, K = 544 ----
    if (wv < 3) {
        const int nl = L & 15, q = L >> 4;
        const char* ap = smemc + nl * 1104 + q * 16;                // A: frame rows
        const _Float16* btp = (const _Float16*)(ws + WS_BT)
                              + (size_t)(wv * 16 + nl) * 544 + q * 8;
        f32x4 acc = {0.0f, 0.0f, 0.0f, 0.0f};
        #pragma unroll
        for (int kk = 0; kk < 17; ++kk) {
            half8 av = *(const half8*)(ap + kk * 64);
            half8 bv = *(const half8*)(btp + kk * 32);
            acc = __builtin_amdgcn_mfma_f32_16x16x32_f16(av, bv, acc, 0, 0, 0);
        }
        const int mel = wv * 16 + nl;
        if (mel < NMEL) {
            #pragma unroll
            for (int r = 0; r < 4; ++r) {
                int fl = q * 4 + r;                 // C/D: row=(lane>>4)*4+r
                lm[fl * NMEL + mel] = (_Float16)__logf(acc[r] + 1e-6f);
            }
        }
    }
    __syncthreads();

    // ---- DCT + scale + lifter, fp32: 208 threads = 16 frames x 13 ceps ----
    if (tid < 16 * NCEP) {
        const int fl = tid / NCEP, c = tid - fl * NCEP;
        float acc = 0.0f;
        #pragma unroll
        for (int m = 0; m < NMEL; ++m)
            acc += (float)lm[fl * NMEL + m] * ws[WS_DT + m * 13 + c];
        out[(size_t)(blockIdx.x * 16 + fl) * (3 * NCEP) + c] = acc;
    }
}

// ---------------------------------------------------------------------------
// Stage 2: per-batch deltas.
// ---------------------------------------------------------------------------
__global__ __launch_bounds__(128) void mfcc_stage2(float* __restrict__ out)
{
    __shared__ float x [NFRAME * NCEP];
    __shared__ float d1[NFRAME * NCEP];

    const int b = blockIdx.x;
    const int tid = threadIdx.x;
    const int TC = NFRAME * NCEP;

    for (int i = tid; i < TC; i += 128) {
        const int t = i / NCEP, c = i - t * NCEP;
        x[i] = out[((size_t)b * NFRAME + t) * (3 * NCEP) + c];
    }
    __syncthreads();

    for (int i = tid; i < TC; i += 128) {
        const int t = i / NCEP, c = i - t * NCEP;
        float acc = 0.0f;
        #pragma unroll
        for (int k = -2; k <= 2; ++k) {
            if (k == 0) continue;
            int tt = t + k;
            tt = tt < 0 ? 0 : (tt > NFRAME - 1 ? NFRAME - 1 : tt);
            acc += (float)k * x[tt * NCEP + c];
        }
        d1[i] = acc * 0.1f;
    }
    __syncthreads();

    for (int i = tid; i < TC; i += 128) {
        const int t = i / NCEP, c = i - t * NCEP;
        float acc = 0.0f;
        #pragma unroll
        for (int k = -2; k <= 2; ++k) {
            if (k == 0) continue;
            int tt = t + k;
            tt = tt < 0 ? 0 : (tt > NFRAME - 1 ? NFRAME - 1 : tt);
            acc += (float)k * d1[tt * NCEP + c];
        }
        const size_t base = ((size_t)b * NFRAME + t) * (3 * NCEP);
        out[base +     NCEP + c] = d1[i];
        out[base + 2 * NCEP + c] = acc * 0.1f;
    }
}

extern "C" void kernel_launch(void* const* d_in, const int* in_sizes, int n_in,
                              void* d_out, int out_size, void* d_ws, size_t ws_size,
                              hipStream_t stream)
{
    const float* wave   = (const float*)d_in[0];   // [1024][16000] f32
    const float* mel_fb = (const float*)d_in[1];   // [513][40] f32
    float* out = (float*)d_out;                    // [1024][49][39][1] f32
    float* ws  = (float*)d_ws;

    mfcc_prep<<<64, 256, 0, stream>>>(mel_fb, ws);
    mfcc_stage1<<<(BATCH * NFRAME) / 16, 256, 0, stream>>>(wave, ws, out);
    mfcc_stage2<<<BATCH, 128, 0, stream>>>(out);
}